// Round 19
// baseline (8453.767 us; speedup 1.0000x reference)
//
#include <hip/hip_runtime.h>

#define S_LEN 256
#define B_SZ  256
#define N_MEM 128
#define D_DIM 256
#define C_DIM 512
#define NBLK  256
#define PROJS 1792
#define AGENT __HIP_MEMORY_SCOPE_AGENT

typedef __bf16 bf16x8 __attribute__((ext_vector_type(8)));
typedef unsigned short ushort4v __attribute__((ext_vector_type(4)));
typedef float floatx4 __attribute__((ext_vector_type(4)));
typedef float floatx2 __attribute__((ext_vector_type(2)));

__device__ __forceinline__ unsigned short f2bf(float f){
  unsigned u = __float_as_uint(f);
  u += 0x7FFFu + ((u >> 16) & 1u);
  return (unsigned short)(u >> 16);
}
__device__ __forceinline__ float bf2f(unsigned short v){
  return __uint_as_float(((unsigned)v) << 16);
}
__device__ __forceinline__ float sigm(float x){ return 1.f/(1.f + __expf(-x)); }
__device__ __forceinline__ floatx4 mfma16(bf16x8 a, bf16x8 b, floatx4 c){
  return __builtin_amdgcn_mfma_f32_16x16x32_bf16(a, b, c, 0, 0, 0);
}

// swizzled memF index: element [n][d] -> n*256 + (((d>>2)^(n&7))<<2 | (d&3))
__device__ __forceinline__ int msw(int n, int d){
  return (n << 8) + ((((d >> 2) ^ (n & 7)) << 2) | (d & 3));
}

// ---- L3-coherent (agent-scope, relaxed) helpers ----
__device__ __forceinline__ unsigned ald32(const void* p){
  return __hip_atomic_load((const unsigned*)p, __ATOMIC_RELAXED, AGENT);
}
__device__ __forceinline__ unsigned long long ald64(const void* p){
  return __hip_atomic_load((const unsigned long long*)p, __ATOMIC_RELAXED, AGENT);
}
__device__ __forceinline__ void ast32(void* p, unsigned v){
  __hip_atomic_store((unsigned*)p, v, __ATOMIC_RELAXED, AGENT);
}
__device__ __forceinline__ void ast64(void* p, unsigned long long v){
  __hip_atomic_store((unsigned long long*)p, v, __ATOMIC_RELAXED, AGENT);
}
__device__ __forceinline__ void sst16(void* p, unsigned short v){
  asm volatile("global_store_short %0, %1, off sc1" :: "v"(p), "v"(v) : "memory");
}
// one coherent 16B load
__device__ __forceinline__ floatx4 cld4(const float* p){
  floatx4 v;
  asm volatile("global_load_dwordx4 %0, %1, off sc1\n\ts_waitcnt vmcnt(0)"
               : "=v"(v) : "v"(p) : "memory");
  return v;
}

struct V16 { floatx4 v0,v1,v2,v3,v4,v5,v6,v7,v8,v9,v10,v11,v12,v13,v14,v15; };
#define BC(xx) __builtin_bit_cast(bf16x8, xx)

// blocking variant: 16 coherent 16B loads + wait
__device__ __forceinline__ V16 cload16(const unsigned short* base){
  V16 r;
  asm volatile(
    "global_load_dwordx4 %0, %16, off sc1\n\t"
    "global_load_dwordx4 %1, %16, off offset:64 sc1\n\t"
    "global_load_dwordx4 %2, %16, off offset:128 sc1\n\t"
    "global_load_dwordx4 %3, %16, off offset:192 sc1\n\t"
    "global_load_dwordx4 %4, %16, off offset:256 sc1\n\t"
    "global_load_dwordx4 %5, %16, off offset:320 sc1\n\t"
    "global_load_dwordx4 %6, %16, off offset:384 sc1\n\t"
    "global_load_dwordx4 %7, %16, off offset:448 sc1\n\t"
    "global_load_dwordx4 %8, %16, off offset:512 sc1\n\t"
    "global_load_dwordx4 %9, %16, off offset:576 sc1\n\t"
    "global_load_dwordx4 %10, %16, off offset:640 sc1\n\t"
    "global_load_dwordx4 %11, %16, off offset:704 sc1\n\t"
    "global_load_dwordx4 %12, %16, off offset:768 sc1\n\t"
    "global_load_dwordx4 %13, %16, off offset:832 sc1\n\t"
    "global_load_dwordx4 %14, %16, off offset:896 sc1\n\t"
    "global_load_dwordx4 %15, %16, off offset:960 sc1\n\t"
    "s_waitcnt vmcnt(0)"
    : "=&v"(r.v0), "=&v"(r.v1), "=&v"(r.v2), "=&v"(r.v3),
      "=&v"(r.v4), "=&v"(r.v5), "=&v"(r.v6), "=&v"(r.v7),
      "=&v"(r.v8), "=&v"(r.v9), "=&v"(r.v10), "=&v"(r.v11),
      "=&v"(r.v12), "=&v"(r.v13), "=&v"(r.v14), "=&v"(r.v15)
    : "v"(base)
    : "memory");
  __builtin_amdgcn_sched_barrier(0);
  return r;
}

// split variant: issue now (no wait), wait later via cwait16
__device__ __forceinline__ void cload16_issue(const unsigned short* base, floatx4 r[16]){
  asm volatile(
    "global_load_dwordx4 %0, %16, off sc1\n\t"
    "global_load_dwordx4 %1, %16, off offset:64 sc1\n\t"
    "global_load_dwordx4 %2, %16, off offset:128 sc1\n\t"
    "global_load_dwordx4 %3, %16, off offset:192 sc1\n\t"
    "global_load_dwordx4 %4, %16, off offset:256 sc1\n\t"
    "global_load_dwordx4 %5, %16, off offset:320 sc1\n\t"
    "global_load_dwordx4 %6, %16, off offset:384 sc1\n\t"
    "global_load_dwordx4 %7, %16, off offset:448 sc1\n\t"
    "global_load_dwordx4 %8, %16, off offset:512 sc1\n\t"
    "global_load_dwordx4 %9, %16, off offset:576 sc1\n\t"
    "global_load_dwordx4 %10, %16, off offset:640 sc1\n\t"
    "global_load_dwordx4 %11, %16, off offset:704 sc1\n\t"
    "global_load_dwordx4 %12, %16, off offset:768 sc1\n\t"
    "global_load_dwordx4 %13, %16, off offset:832 sc1\n\t"
    "global_load_dwordx4 %14, %16, off offset:896 sc1\n\t"
    "global_load_dwordx4 %15, %16, off offset:960 sc1"
    : "=&v"(r[0]), "=&v"(r[1]), "=&v"(r[2]), "=&v"(r[3]),
      "=&v"(r[4]), "=&v"(r[5]), "=&v"(r[6]), "=&v"(r[7]),
      "=&v"(r[8]), "=&v"(r[9]), "=&v"(r[10]), "=&v"(r[11]),
      "=&v"(r[12]), "=&v"(r[13]), "=&v"(r[14]), "=&v"(r[15])
    : "v"(base)
    : "memory");
}
__device__ __forceinline__ void cwait16(floatx4 r[16]){
  asm volatile("s_waitcnt vmcnt(0)"
    : "+v"(r[0]), "+v"(r[1]), "+v"(r[2]), "+v"(r[3]),
      "+v"(r[4]), "+v"(r[5]), "+v"(r[6]), "+v"(r[7]),
      "+v"(r[8]), "+v"(r[9]), "+v"(r[10]), "+v"(r[11]),
      "+v"(r[12]), "+v"(r[13]), "+v"(r[14]), "+v"(r[15])
    :: "memory");
  __builtin_amdgcn_sched_barrier(0);
}

// ---------------- prologue kernels ----------------

__global__ __launch_bounds__(256) void p0_xbf(const float* __restrict__ x,
                                              unsigned short* __restrict__ xbf){
  int idx = (blockIdx.x*256 + threadIdx.x)*4;
  floatx4 f = *(const floatx4*)(x + idx);
  ushort4v u;
  u[0]=f2bf(f[0]); u[1]=f2bf(f[1]); u[2]=f2bf(f[2]); u[3]=f2bf(f[3]);
  *(ushort4v*)(xbf + idx) = u;
}

__global__ __launch_bounds__(256) void p1_wg(const float* __restrict__ Wih,
                                             const float* __restrict__ Whh,
                                             unsigned short* __restrict__ Wg){
  int idx = blockIdx.x*256 + threadIdx.x;
  int n = idx / 768, k = idx - n*768;
  float v = (k < 256) ? Wih[n*256 + k] : Whh[n*512 + (k-256)];
  Wg[idx] = f2bf(v);
}

__global__ __launch_bounds__(256) void p2_T(const float* __restrict__ Win,
                                            const float* __restrict__ Wread,
                                            const float* __restrict__ bread,
                                            const float* __restrict__ bin,
                                            float* __restrict__ T, float* __restrict__ rq){
  if (blockIdx.x < 512){
    int idx = blockIdx.x*256 + threadIdx.x;
    int e = idx >> 9, cc = idx & 511;
    float acc = 0.f;
    for (int dp = 0; dp < 256; ++dp) acc += Win[e*256 + dp] * Wread[dp*512 + cc];
    T[idx] = acc;
  } else {
    int e = threadIdx.x;
    float acc = bin[e];
    for (int dp = 0; dp < 256; ++dp) acc += bread[dp] * Win[e*256 + dp];
    rq[e] = acc;
  }
}

__global__ __launch_bounds__(256) void p3_w2(const float* __restrict__ Win,
                                             const float* __restrict__ Wwrite,
                                             const float* __restrict__ Werase,
                                             const float* __restrict__ Wrg,
                                             const float* __restrict__ Wwg,
                                             const float* __restrict__ bwrite,
                                             const float* __restrict__ berase,
                                             const float* __restrict__ brg,
                                             const float* __restrict__ bwg,
                                             const float* __restrict__ T,
                                             const float* __restrict__ rq,
                                             unsigned short* __restrict__ W2,
                                             float* __restrict__ bias2){
  int bid = blockIdx.x;
  if (bid < 2048){
    int idx = bid*256 + threadIdx.x;
    int j = idx >> 9, cc = idx & 511;
    int h = j >> 8, d = j & 255;
    float acc = 0.f;
    const float* wk = Win + (256 + h*64)*256 + d;
    const float* tp = T + (h*64)*512 + cc;
    for (int i = 0; i < 64; ++i) acc += wk[i*256] * tp[i*512];
    W2[(size_t)j*512 + cc] = f2bf(acc);
  } else if (bid < 2048 + 1568){
    int idx = (bid - 2048)*256 + threadIdx.x;
    int r = idx >> 9, cc = idx & 511;
    float v;
    if      (r < 512) v = Wwrite[r*512 + cc];
    else if (r < 768) v = Werase[(r-512)*512 + cc];
    else if (r == 768) v = Wrg[cc];
    else if (r == 769) v = Wwg[cc];
    else v = 0.f;
    W2[(size_t)(1024 + r)*512 + cc] = f2bf(v);
  } else {
    int j = (bid - 2048 - 1568)*256 + threadIdx.x;
    if (j >= 1808) return;
    float v;
    if (j < 1024){
      int h = j >> 8, d = j & 255;
      float acc = 0.f;
      for (int i = 0; i < 64; ++i) acc += rq[h*64+i] * Win[(256 + h*64 + i)*256 + d];
      v = acc;
    }
    else if (j < 1536) v = bwrite[j - 1024];
    else if (j < 1792) v = berase[j - 1536];
    else if (j == 1792) v = brg[0];
    else if (j == 1793) v = bwg[0];
    else v = 0.f;
    bias2[j] = v;
  }
}

// Fold: column j = d*4 + h (matches mctx u64-packed d-major layout)
__global__ __launch_bounds__(256) void p4_fold(const float* __restrict__ Win,
                                               const float* __restrict__ Wout,
                                               const float* __restrict__ bout,
                                               const float* __restrict__ bin,
                                               unsigned short* __restrict__ Fold,
                                               float* __restrict__ bout2){
  if (blockIdx.x < 1024){
    int idx = blockIdx.x*256 + threadIdx.x;
    int dp = idx >> 10, j = idx & 1023;
    int h = j & 3, d = j >> 2;
    float acc = 0.f;
    const float* wv = Win + (512 + h*64)*256 + d;
    const float* wo = Wout + dp*256 + h*64;
    for (int i = 0; i < 64; ++i) acc += wv[i*256] * wo[i];
    Fold[(size_t)dp*1024 + j] = f2bf(acc);
  } else {
    int dp = threadIdx.x;
    float acc = bout[dp];
    for (int e = 0; e < 256; ++e) acc += Wout[dp*256 + e] * bin[512 + e];
    bout2[dp] = acc;
  }
}

// zero c/h0, biasg = bih + bhh
__global__ __launch_bounds__(256) void p5_init(const float* __restrict__ bih,
                                               const float* __restrict__ bhh,
                                               float* __restrict__ biasg,
                                               float* __restrict__ c,
                                               unsigned short* __restrict__ h0){
  int idx = blockIdx.x*256 + threadIdx.x;
  c[idx] = 0.f; h0[idx] = 0;
  if (idx < 2048) biasg[idx] = bih[idx] + bhh[idx];
}

// ---------------- flag group barrier, lane-parallel poll ----------------
// Arrive: plain relaxed store of epoch into own slot (data already drained by
// __syncthreads). Poll: lanes 0..15 of wave 0 load the 16 slots of ONE 64B
// line in a single coalesced instruction; one __all ballot per iteration.
__device__ __forceinline__ void gbarw(unsigned* slots, int uc, unsigned epoch){
  __syncthreads();
  if (threadIdx.x < 64){
    if (threadIdx.x == 0) ast32(&slots[uc], epoch);
    for (;;){
      unsigned v = (threadIdx.x < 16) ? ald32(&slots[threadIdx.x]) : epoch;
      if (__all((int)(v >= epoch))) break;
      __builtin_amdgcn_s_sleep(1);
    }
  }
  __builtin_amdgcn_sched_barrier(0);
  __syncthreads();
}

// ---------------- persistent kernel ----------------

// full-load readout (final step only)
__device__ __forceinline__ void do_readout(int mt, int dt, int t,
                                           const unsigned short* __restrict__ mctx,
                                           const unsigned short* __restrict__ Fold,
                                           const float* __restrict__ rgb,
                                           const float* __restrict__ bout2,
                                           const float* __restrict__ x,
                                           float* __restrict__ out, int lane){
  const int lm = lane & 15, lk = (lane >> 4) * 8;
  const unsigned short* ap = mctx + (size_t)(mt*16 + lm)*1024 + lk;
  const unsigned short* bp = Fold + (size_t)(dt*16 + lm)*1024 + lk;
  const int r0 = mt*16 + ((lane >> 4) << 2);
  floatx4 rg = cld4(&rgb[r0]);
  V16 a0 = cload16(ap);
  V16 a1 = cload16(ap + 512);
  const bf16x8 av[16] = {BC(a0.v0),BC(a0.v1),BC(a0.v2),BC(a0.v3),BC(a0.v4),BC(a0.v5),BC(a0.v6),BC(a0.v7),
                         BC(a0.v8),BC(a0.v9),BC(a0.v10),BC(a0.v11),BC(a0.v12),BC(a0.v13),BC(a0.v14),BC(a0.v15)};
  const bf16x8 bv[16] = {BC(a1.v0),BC(a1.v1),BC(a1.v2),BC(a1.v3),BC(a1.v4),BC(a1.v5),BC(a1.v6),BC(a1.v7),
                         BC(a1.v8),BC(a1.v9),BC(a1.v10),BC(a1.v11),BC(a1.v12),BC(a1.v13),BC(a1.v14),BC(a1.v15)};
  floatx4 acc = {0,0,0,0};
  #pragma unroll
  for (int kt = 0; kt < 16; ++kt)
    acc = mfma16(av[kt], *(const bf16x8*)(bp + kt*32), acc);
  #pragma unroll
  for (int kt = 0; kt < 16; ++kt)
    acc = mfma16(bv[kt], *(const bf16x8*)(bp + 512 + kt*32), acc);
  const int dp = dt*16 + lm;
  const float bo = bout2[dp];
  #pragma unroll
  for (int q = 0; q < 4; ++q){
    const int bb = r0 + q;
    const size_t oi = ((size_t)bb * S_LEN + (t-1)) * D_DIM + dp;
    out[oi] = x[oi] + rg[q] * (acc[q] + bo);
  }
}

// readout with preloaded Fold first half (in-loop)
__device__ __forceinline__ void do_readout_pre(const bf16x8 f1[16],
                                               int mt, int dt, int t,
                                               const unsigned short* __restrict__ mctx,
                                               const unsigned short* __restrict__ Fold,
                                               const float* __restrict__ rgb,
                                               const float* __restrict__ bout2,
                                               const float* __restrict__ x,
                                               float* __restrict__ out, int lane){
  const int lm = lane & 15, lk = (lane >> 4) * 8;
  const unsigned short* ap = mctx + (size_t)(mt*16 + lm)*1024 + lk;
  const unsigned short* bp = Fold + (size_t)(dt*16 + lm)*1024 + lk;
  const int r0 = mt*16 + ((lane >> 4) << 2);
  floatx4 rg = cld4(&rgb[r0]);
  V16 a0 = cload16(ap);
  V16 a1 = cload16(ap + 512);
  const bf16x8 av[16] = {BC(a0.v0),BC(a0.v1),BC(a0.v2),BC(a0.v3),BC(a0.v4),BC(a0.v5),BC(a0.v6),BC(a0.v7),
                         BC(a0.v8),BC(a0.v9),BC(a0.v10),BC(a0.v11),BC(a0.v12),BC(a0.v13),BC(a0.v14),BC(a0.v15)};
  const bf16x8 bv[16] = {BC(a1.v0),BC(a1.v1),BC(a1.v2),BC(a1.v3),BC(a1.v4),BC(a1.v5),BC(a1.v6),BC(a1.v7),
                         BC(a1.v8),BC(a1.v9),BC(a1.v10),BC(a1.v11),BC(a1.v12),BC(a1.v13),BC(a1.v14),BC(a1.v15)};
  floatx4 acc = {0,0,0,0};
  #pragma unroll
  for (int kt = 0; kt < 16; ++kt)
    acc = mfma16(av[kt], f1[kt], acc);
  #pragma unroll
  for (int kt = 0; kt < 16; ++kt)
    acc = mfma16(bv[kt], *(const bf16x8*)(bp + 512 + kt*32), acc);
  const int dp = dt*16 + lm;
  const float bo = bout2[dp];
  #pragma unroll
  for (int q = 0; q < 4; ++q){
    const int bb = r0 + q;
    const size_t oi = ((size_t)bb * S_LEN + (t-1)) * D_DIM + dp;
    out[oi] = x[oi] + rg[q] * (acc[q] + bo);
  }
}

__global__ __launch_bounds__(512, 2) void kmain(
    const float* __restrict__ x,
    const unsigned short* __restrict__ xbf,
    const unsigned short* __restrict__ Wg,
    const float* __restrict__ biasg,
    const unsigned short* __restrict__ W2, const float* __restrict__ bias2,
    const unsigned short* __restrict__ Fold, const float* __restrict__ bout2,
    float* __restrict__ cbuf,
    unsigned short* __restrict__ h0buf, unsigned short* __restrict__ h1buf,
    unsigned short* __restrict__ projB, unsigned short* __restrict__ mctx,
    float* __restrict__ rgbuf, const float* __restrict__ mem0,
    float* __restrict__ memT, float* __restrict__ out,
    unsigned* __restrict__ barcnt)
{
  const int bid = blockIdx.x, tid = threadIdx.x;
  const int lane = tid & 63, wave = tid >> 6;
  const int lm = lane & 15, lk = (lane >> 4) * 8;

  __shared__ float memF[32768];       // 131072 B, XOR-swizzled [n][d]
  __shared__ float scU[5][512];       //  10240 B (AB: ga / D: scores)
  __shared__ float qkW[5][256];       //   5120 B
  __shared__ float er[256];           //   1024 B
  __shared__ float wvs[256];          //   1024 B
  __shared__ float attT[128][8];      //   4096 B
  __shared__ float hL[512];           //   2048 B
  __shared__ float wgS;
  float (*ga)[16][32] = (float (*)[16][32])&scU[0][0];

  const int r = bid >> 4, uc = bid & 15, u0 = uc*32;
  unsigned* gslots = barcnt + r*64;   // 16 flags in one 64B line; 256B per group

  for (int i = tid; i < 32768; i += 512){
    const int n = i >> 8, d = i & 255;
    memF[msw(n, d)] = mem0[i];
  }

  unsigned nbar = 0;
  const unsigned short* hr = h0buf;
  unsigned short* hw = h1buf;
  const int g = wave >> 1, colh = wave & 1;
  const int row = r*16 + lm;
  const int slot = uc*8 + wave;       // 0..127 within group

  // ---- weight preload (spills to scratch; measured neutral-positive, R13) ----
  bf16x8 whreg[16];
  {
    const unsigned short* wb = Wg + (size_t)(g*512 + u0 + colh*16 + lm)*768 + lk;
    #pragma unroll
    for (int kt = 0; kt < 16; ++kt) whreg[kt] = *(const bf16x8*)(wb + 256 + kt*32);
  }
  bf16x8 w2reg[16];
  if (slot < 112){
    const unsigned short* bp = W2 + (size_t)(slot*16 + lm)*512 + lk;
    #pragma unroll
    for (int kt = 0; kt < 16; ++kt) w2reg[kt] = *(const bf16x8*)(bp + kt*32);
  } else {
    const unsigned short* bp = Fold + (size_t)((slot-112)*16 + lm)*1024 + lk;
    #pragma unroll
    for (int kt = 0; kt < 16; ++kt) w2reg[kt] = *(const bf16x8*)(bp + kt*32);
  }

  // prologue prefetch: h(-1)=0 buffer + x(0)
  floatx4 hq[16];
  bf16x8 xfr[8];
  cload16_issue(hr + (size_t)row*C_DIM + lk, hq);
  {
    const unsigned short* ax = xbf + ((size_t)row*S_LEN + 0)*D_DIM + lk;
    #pragma unroll
    for (int kt = 0; kt < 8; ++kt) xfr[kt] = *(const bf16x8*)(ax + kt*32);
  }

  for (int t = 0; t < S_LEN; ++t){
    // ---- phase AB: gates GEMM + LSTM ----
    {
      const unsigned short* wbx = Wg + (size_t)(g*512 + u0 + colh*16 + lm)*768 + lk;
      cwait16(hq);
      floatx4 acc = {0,0,0,0};
      #pragma unroll
      for (int kt = 0; kt < 8; ++kt)
        acc = mfma16(xfr[kt], *(const bf16x8*)(wbx + kt*32), acc);
      #pragma unroll
      for (int kt = 0; kt < 16; ++kt)
        acc = mfma16(BC(hq[kt]), whreg[kt], acc);
      const int rr0 = (lane >> 4) << 2;
      #pragma unroll
      for (int q = 0; q < 4; ++q) ga[g][rr0+q][colh*16 + lm] = acc[q];
      __syncthreads();
      if (tid < 256){
        const int ri = tid >> 4, cp = (tid & 15) * 2;
        const int b = r*16 + ri, u = u0 + cp;
        floatx2 bg0 = *(const floatx2*)&biasg[u];
        floatx2 bg1 = *(const floatx2*)&biasg[512 + u];
        floatx2 bg2 = *(const floatx2*)&biasg[1024 + u];
        floatx2 bg3 = *(const floatx2*)&biasg[1536 + u];
        const float gi0 = ga[0][ri][cp]   + bg0[0];
        const float gf0 = ga[1][ri][cp]   + bg1[0];
        const float gg0 = ga[2][ri][cp]   + bg2[0];
        const float go0 = ga[3][ri][cp]   + bg3[0];
        const float gi1 = ga[0][ri][cp+1] + bg0[1];
        const float gf1 = ga[1][ri][cp+1] + bg1[1];
        const float gg1 = ga[2][ri][cp+1] + bg2[1];
        const float go1 = ga[3][ri][cp+1] + bg3[1];
        const int ci2 = b*512 + u;
        floatx2 cv = *(const floatx2*)&cbuf[ci2];
        const float cn0 = sigm(gf0) * cv[0] + sigm(gi0) * tanhf(gg0);
        const float cn1 = sigm(gf1) * cv[1] + sigm(gi1) * tanhf(gg1);
        floatx2 cw; cw[0] = cn0; cw[1] = cn1;
        *(floatx2*)&cbuf[ci2] = cw;
        const unsigned hv2 = (unsigned)f2bf(sigm(go0) * tanhf(cn0))
                           | ((unsigned)f2bf(sigm(go1) * tanhf(cn1)) << 16);
        ast32((unsigned*)hw + (ci2 >> 1), hv2);
      }
    }
    gbarw(gslots, uc, ++nbar);
    // ---- phase C: 112 proj tiles + 16 readouts ----
    {
      if (slot < 112){
        const unsigned short* ap = hw + (size_t)(r*16 + lm)*512 + lk;
        V16 av16 = cload16(ap);
        const bf16x8 av[16] = {BC(av16.v0),BC(av16.v1),BC(av16.v2),BC(av16.v3),BC(av16.v4),BC(av16.v5),BC(av16.v6),BC(av16.v7),
                               BC(av16.v8),BC(av16.v9),BC(av16.v10),BC(av16.v11),BC(av16.v12),BC(av16.v13),BC(av16.v14),BC(av16.v15)};
        floatx4 acc = {0,0,0,0};
        #pragma unroll
        for (int kt = 0; kt < 16; ++kt)
          acc = mfma16(av[kt], w2reg[kt], acc);
        const int r0 = r*16 + ((lane >> 4) << 2);
        const int cc = slot*16 + lm;
        const float bv = bias2[cc];
        const bool sg = (cc >= 1536);
        #pragma unroll
        for (int q = 0; q < 4; ++q){
          float v = acc[q] + bv;
          if (sg) v = sigm(v);
          sst16(&projB[(size_t)(r0 + q)*PROJS + cc], f2bf(v));
        }
      } else if (t >= 1){
        do_readout_pre(w2reg, r, slot - 112, t, mctx, Fold, rgbuf, bout2, x, out, lane);
      }
    }
    gbarw(gslots, uc, ++nbar);
    // ---- phase D: attention + memory update (block = batch bid) ----
    {
      const unsigned long long* p64 = (const unsigned long long*)(projB + (size_t)bid*PROJS);
      if (tid < 448){
        unsigned long long u2 = ald64(p64 + tid);
        float e0 = bf2f((unsigned short)(u2 & 0xFFFFu));
        float e1 = bf2f((unsigned short)((u2 >> 16) & 0xFFFFu));
        float e2 = bf2f((unsigned short)((u2 >> 32) & 0xFFFFu));
        float e3 = bf2f((unsigned short)(u2 >> 48));
        const int j = tid*4;
        if (j < 1024){ float* q = &qkW[j>>8][j&255]; q[0]=e0; q[1]=e1; q[2]=e2; q[3]=e3; }
        else if (j < 1280){ float* q = &qkW[4][j-1024]; q[0]=e0; q[1]=e1; q[2]=e2; q[3]=e3; }
        else if (j < 1536){ float* q = &wvs[j-1280]; q[0]=e0; q[1]=e1; q[2]=e2; q[3]=e3; }
        else { float* q = &er[j-1536]; q[0]=e0; q[1]=e1; q[2]=e2; q[3]=e3; }
      } else {
        const int i = tid - 448;
        const unsigned long long* h64 = (const unsigned long long*)(hw + (size_t)bid*C_DIM);
        unsigned long long a = ald64(h64 + 2*i), b = ald64(h64 + 2*i + 1);
        float* q = &hL[i*8];
        q[0]=bf2f((unsigned short)(a & 0xFFFFu)); q[1]=bf2f((unsigned short)((a>>16)&0xFFFFu));
        q[2]=bf2f((unsigned short)((a>>32)&0xFFFFu)); q[3]=bf2f((unsigned short)(a>>48));
        q[4]=bf2f((unsigned short)(b & 0xFFFFu)); q[5]=bf2f((unsigned short)((b>>16)&0xFFFFu));
        q[6]=bf2f((unsigned short)((b>>32)&0xFFFFu)); q[7]=bf2f((unsigned short)(b>>48));
      }
      __syncthreads();
      if (wave >= 6){
        const int rowW = 1792 + (wave - 6);
        const unsigned short* wrow = W2 + (size_t)rowW*512 + lane*8;
        const float* hp = &hL[lane*8];
        float s = 0.f;
        #pragma unroll
        for (int c = 0; c < 8; ++c) s += hp[c] * bf2f(wrow[c]);
        #pragma unroll
        for (int off = 32; off; off >>= 1) s += __shfl_xor(s, off);
        if (lane == 0){
          const float v = sigm(s + bias2[rowW]);
          if (wave == 6) ast32(&rgbuf[bid], __float_as_uint(v));
          else wgS = v;
        }
      }
      // pass1: scores (vectorized b128, swizzle-aware)
      {
        const int n = tid & 127, quarter = tid >> 7, db = quarter*64;
        const int c7 = n & 7;
        const float* mrow = &memF[n << 8];
        floatx4 A0={0,0,0,0},A1={0,0,0,0},A2={0,0,0,0},A3={0,0,0,0},A4={0,0,0,0};
        #pragma unroll 4
        for (int i = 0; i < 64; i += 4){
          floatx4 m4 = *(const floatx4*)(mrow + ((((db+i)>>2) ^ c7) << 2));
          floatx4 q0 = *(const floatx4*)&qkW[0][db+i];
          floatx4 q1 = *(const floatx4*)&qkW[1][db+i];
          floatx4 q2 = *(const floatx4*)&qkW[2][db+i];
          floatx4 q3 = *(const floatx4*)&qkW[3][db+i];
          floatx4 qw = *(const floatx4*)&qkW[4][db+i];
          A0 += m4*q0; A1 += m4*q1; A2 += m4*q2; A3 += m4*q3; A4 += m4*qw;
        }
        scU[0][tid] = A0[0]+A0[1]+A0[2]+A0[3];
        scU[1][tid] = A1[0]+A1[1]+A1[2]+A1[3];
        scU[2][tid] = A2[0]+A2[1]+A2[2]+A2[3];
        scU[3][tid] = A3[0]+A3[1]+A3[2]+A3[3];
        scU[4][tid] = A4[0]+A4[1]+A4[2]+A4[3];
      }
      __syncthreads();
      if (tid < 128){
        #pragma unroll
        for (int j = 0; j < 5; ++j){
          float v = scU[j][tid] + scU[j][tid+128] + scU[j][tid+256] + scU[j][tid+384];
          scU[j][tid] = (j < 4) ? v * 0.125f : v;
        }
      }
      __syncthreads();
      {
        const int w = tid >> 6, l = tid & 63;
        if (w < 5){
          const int j = w;
          float v0 = scU[j][l], v1 = scU[j][l + 64];
          float mx = fmaxf(v0, v1);
          #pragma unroll
          for (int off = 32; off; off >>= 1) mx = fmaxf(mx, __shfl_xor(mx, off));
          float e0 = __expf(v0 - mx), e1 = __expf(v1 - mx);
          float sm = e0 + e1;
          #pragma unroll
          for (int off = 32; off; off >>= 1) sm += __shfl_xor(sm, off);
          float inv = 1.f / sm;
          attT[l][j] = e0 * inv; attT[l + 64][j] = e1 * inv;
        }
      }
      __syncthreads();
      // prefetch x(t+1) + issue h(t) coherent loads — latency hides under pass2
      {
        const int tn = (t+1 < S_LEN) ? t+1 : t;
        const unsigned short* ax = xbf + ((size_t)row*S_LEN + tn)*D_DIM + lk;
        #pragma unroll
        for (int kt = 0; kt < 8; ++kt) xfr[kt] = *(const bf16x8*)(ax + kt*32);
        cload16_issue(hw + (size_t)row*C_DIM + lk, hq);
      }
      // fused pass2 + memory update
      {
        const float wgv = wgS;
        const int dlow = lane & 7, ng = lane >> 3;
        const int dblk = wave*8 + dlow;
        const int pblk = dblk ^ ng;
        const int d4 = dblk*4;
        floatx4 er4 = *(const floatx4*)&er[d4];
        floatx4 wv4 = *(const floatx4*)&wvs[d4];
        floatx4 A0={0,0,0,0},A1={0,0,0,0},A2={0,0,0,0},A3={0,0,0,0};
        #pragma unroll 4
        for (int k = 0; k < 16; ++k){
          const int n = ng + k*8;
          float* maddr = &memF[(n << 8) + (pblk << 2)];
          floatx4 m = *(const floatx4*)maddr;
          floatx4 a4 = *(const floatx4*)&attT[n][0];
          const float aw = attT[n][4];
          A0 += a4[0]*m; A1 += a4[1]*m; A2 += a4[2]*m; A3 += a4[3]*m;
          m = m * (1.f - aw*er4) + (wgv*aw) * wv4;
          *(floatx4*)maddr = m;
        }
        #pragma unroll
        for (int off = 8; off <= 32; off <<= 1){
          #pragma unroll
          for (int c = 0; c < 4; ++c){
            A0[c] += __shfl_xor(A0[c], off);
            A1[c] += __shfl_xor(A1[c], off);
            A2[c] += __shfl_xor(A2[c], off);
            A3[c] += __shfl_xor(A3[c], off);
          }
        }
        if (ng == 0){
          unsigned long long* mrow2 = (unsigned long long*)(mctx + (size_t)bid*1024);
          #pragma unroll
          for (int dd = 0; dd < 4; ++dd){
            const unsigned lo = (unsigned)f2bf(A0[dd]) | ((unsigned)f2bf(A1[dd]) << 16);
            const unsigned hi = (unsigned)f2bf(A2[dd]) | ((unsigned)f2bf(A3[dd]) << 16);
            ast64(mrow2 + d4 + dd, (unsigned long long)lo | ((unsigned long long)hi << 32));
          }
        }
      }
    }
    unsigned short* tmp = (unsigned short*)hr; hr = hw; hw = tmp;
  }
  gbarw(gslots, uc, ++nbar);
  // final readout (t = S_LEN): one tile per block (mt=r, dt=uc)
  if (wave == 0)
    do_readout(r, uc, S_LEN, mctx, Fold, rgbuf, bout2, x, out, lane);
  for (int i = tid; i < 32768; i += 512){
    const int n = i >> 8, d = i & 255;
    memT[(size_t)bid * 32768 + i] = memF[msw(n, d)];
  }
}

// ---------------- host ----------------

extern "C" void kernel_launch(void* const* d_in, const int* in_sizes, int n_in,
                              void* d_out, int out_size, void* d_ws, size_t ws_size,
                              hipStream_t stream){
  const float* x      = (const float*)d_in[0];
  const float* mem0   = (const float*)d_in[1];
  const float* Wih    = (const float*)d_in[2];
  const float* Whh    = (const float*)d_in[3];
  const float* bih    = (const float*)d_in[4];
  const float* bhh    = (const float*)d_in[5];
  const float* Wread  = (const float*)d_in[6];
  const float* bread  = (const float*)d_in[7];
  const float* Wwrite = (const float*)d_in[8];
  const float* bwrite = (const float*)d_in[9];
  const float* Werase = (const float*)d_in[10];
  const float* berase = (const float*)d_in[11];
  const float* Win    = (const float*)d_in[12];
  const float* bin    = (const float*)d_in[13];
  const float* Wout   = (const float*)d_in[14];
  const float* bout   = (const float*)d_in[15];
  const float* Wrg    = (const float*)d_in[16];
  const float* brg    = (const float*)d_in[17];
  const float* Wwg    = (const float*)d_in[18];
  const float* bwg    = (const float*)d_in[19];
  float* out = (float*)d_out;
  float* memT = out + (size_t)B_SZ * S_LEN * D_DIM;

  char* ws = (char*)d_ws;
  size_t off = 0;
  auto alloc = [&](size_t bytes) -> void* {
    void* p = ws + off; off += (bytes + 511) & ~(size_t)511; return p;
  };
  unsigned short* xbf  = (unsigned short*)alloc((size_t)B_SZ*S_LEN*D_DIM*2);
  unsigned short* Wg   = (unsigned short*)alloc((size_t)2048*768*2);
  unsigned short* W2   = (unsigned short*)alloc((size_t)1808*512*2);
  unsigned short* Fold = (unsigned short*)alloc((size_t)256*1024*2);
  float* T     = (float*)alloc((size_t)256*512*4);
  float* rq    = (float*)alloc(256*4);
  float* bias2 = (float*)alloc(1808*4);
  float* bout2 = (float*)alloc(256*4);
  float* biasg = (float*)alloc(2048*4);
  float* cbuf  = (float*)alloc((size_t)256*512*4);
  unsigned short* h0 = (unsigned short*)alloc((size_t)256*512*2);
  unsigned short* h1 = (unsigned short*)alloc((size_t)256*512*2);
  unsigned short* projB = (unsigned short*)alloc((size_t)256*PROJS*2);
  unsigned short* mctx = (unsigned short*)alloc((size_t)256*1024*2);
  float* rgbuf = (float*)alloc(256*4);
  unsigned* barcnt = (unsigned*)alloc(16384);
  (void)ws_size; (void)in_sizes; (void)n_in; (void)out_size;

  (void)hipMemsetAsync(barcnt, 0, 16384, stream);
  p0_xbf <<<16384, 256, 0, stream>>>(x, xbf);
  p1_wg  <<<6144, 256, 0, stream>>>(Wih, Whh, Wg);
  p2_T   <<<513,  256, 0, stream>>>(Win, Wread, bread, bin, T, rq);
  p3_w2  <<<3624, 256, 0, stream>>>(Win, Wwrite, Werase, Wrg, Wwg, bwrite, berase, brg, bwg, T, rq, W2, bias2);
  p4_fold<<<1025, 256, 0, stream>>>(Win, Wout, bout, bin, Fold, bout2);
  p5_init<<<512,  256, 0, stream>>>(bih, bhh, biasg, cbuf, h0);

  kmain<<<NBLK, 512, 0, stream>>>(x, xbf, Wg, biasg, W2, bias2, Fold, bout2,
                                  cbuf, h0, h1, projB, mctx, rgbuf, mem0, memT, out, barcnt);
}

// Round 20
// 8306.691 us; speedup vs baseline: 1.0177x; 1.0177x over previous
//
#include <hip/hip_runtime.h>

#define S_LEN 256
#define B_SZ  256
#define N_MEM 128
#define D_DIM 256
#define C_DIM 512
#define NBLK  256
#define PROJS 1792
#define AGENT __HIP_MEMORY_SCOPE_AGENT

typedef __bf16 bf16x8 __attribute__((ext_vector_type(8)));
typedef unsigned short ushort4v __attribute__((ext_vector_type(4)));
typedef float floatx4 __attribute__((ext_vector_type(4)));
typedef float floatx2 __attribute__((ext_vector_type(2)));

__device__ __forceinline__ unsigned short f2bf(float f){
  unsigned u = __float_as_uint(f);
  u += 0x7FFFu + ((u >> 16) & 1u);
  return (unsigned short)(u >> 16);
}
__device__ __forceinline__ float bf2f(unsigned short v){
  return __uint_as_float(((unsigned)v) << 16);
}
__device__ __forceinline__ float sigm(float x){ return 1.f/(1.f + __expf(-x)); }
__device__ __forceinline__ floatx4 mfma16(bf16x8 a, bf16x8 b, floatx4 c){
  return __builtin_amdgcn_mfma_f32_16x16x32_bf16(a, b, c, 0, 0, 0);
}

// swizzled memF index: element [n][d] -> n*256 + (((d>>2)^(n&7))<<2 | (d&3))
__device__ __forceinline__ int msw(int n, int d){
  return (n << 8) + ((((d >> 2) ^ (n & 7)) << 2) | (d & 3));
}

// ---- L3-coherent (agent-scope, relaxed) helpers ----
__device__ __forceinline__ unsigned ald32(const void* p){
  return __hip_atomic_load((const unsigned*)p, __ATOMIC_RELAXED, AGENT);
}
__device__ __forceinline__ unsigned long long ald64(const void* p){
  return __hip_atomic_load((const unsigned long long*)p, __ATOMIC_RELAXED, AGENT);
}
__device__ __forceinline__ void ast32(void* p, unsigned v){
  __hip_atomic_store((unsigned*)p, v, __ATOMIC_RELAXED, AGENT);
}
__device__ __forceinline__ void ast64(void* p, unsigned long long v){
  __hip_atomic_store((unsigned long long*)p, v, __ATOMIC_RELAXED, AGENT);
}
__device__ __forceinline__ void sst16(void* p, unsigned short v){
  asm volatile("global_store_short %0, %1, off sc1" :: "v"(p), "v"(v) : "memory");
}
// one coherent 16B load (replaces 4 serial ald32 on the readout path)
__device__ __forceinline__ floatx4 cld4(const float* p){
  floatx4 v;
  asm volatile("global_load_dwordx4 %0, %1, off sc1\n\ts_waitcnt vmcnt(0)"
               : "=v"(v) : "v"(p) : "memory");
  return v;
}

struct V16 { floatx4 v0,v1,v2,v3,v4,v5,v6,v7,v8,v9,v10,v11,v12,v13,v14,v15; };
#define BC(xx) __builtin_bit_cast(bf16x8, xx)

// blocking variant: 16 coherent 16B loads + wait
__device__ __forceinline__ V16 cload16(const unsigned short* base){
  V16 r;
  asm volatile(
    "global_load_dwordx4 %0, %16, off sc1\n\t"
    "global_load_dwordx4 %1, %16, off offset:64 sc1\n\t"
    "global_load_dwordx4 %2, %16, off offset:128 sc1\n\t"
    "global_load_dwordx4 %3, %16, off offset:192 sc1\n\t"
    "global_load_dwordx4 %4, %16, off offset:256 sc1\n\t"
    "global_load_dwordx4 %5, %16, off offset:320 sc1\n\t"
    "global_load_dwordx4 %6, %16, off offset:384 sc1\n\t"
    "global_load_dwordx4 %7, %16, off offset:448 sc1\n\t"
    "global_load_dwordx4 %8, %16, off offset:512 sc1\n\t"
    "global_load_dwordx4 %9, %16, off offset:576 sc1\n\t"
    "global_load_dwordx4 %10, %16, off offset:640 sc1\n\t"
    "global_load_dwordx4 %11, %16, off offset:704 sc1\n\t"
    "global_load_dwordx4 %12, %16, off offset:768 sc1\n\t"
    "global_load_dwordx4 %13, %16, off offset:832 sc1\n\t"
    "global_load_dwordx4 %14, %16, off offset:896 sc1\n\t"
    "global_load_dwordx4 %15, %16, off offset:960 sc1\n\t"
    "s_waitcnt vmcnt(0)"
    : "=&v"(r.v0), "=&v"(r.v1), "=&v"(r.v2), "=&v"(r.v3),
      "=&v"(r.v4), "=&v"(r.v5), "=&v"(r.v6), "=&v"(r.v7),
      "=&v"(r.v8), "=&v"(r.v9), "=&v"(r.v10), "=&v"(r.v11),
      "=&v"(r.v12), "=&v"(r.v13), "=&v"(r.v14), "=&v"(r.v15)
    : "v"(base)
    : "memory");
  __builtin_amdgcn_sched_barrier(0);
  return r;
}

// split variant: issue now (no wait), wait later via cwait16
__device__ __forceinline__ void cload16_issue(const unsigned short* base, floatx4 r[16]){
  asm volatile(
    "global_load_dwordx4 %0, %16, off sc1\n\t"
    "global_load_dwordx4 %1, %16, off offset:64 sc1\n\t"
    "global_load_dwordx4 %2, %16, off offset:128 sc1\n\t"
    "global_load_dwordx4 %3, %16, off offset:192 sc1\n\t"
    "global_load_dwordx4 %4, %16, off offset:256 sc1\n\t"
    "global_load_dwordx4 %5, %16, off offset:320 sc1\n\t"
    "global_load_dwordx4 %6, %16, off offset:384 sc1\n\t"
    "global_load_dwordx4 %7, %16, off offset:448 sc1\n\t"
    "global_load_dwordx4 %8, %16, off offset:512 sc1\n\t"
    "global_load_dwordx4 %9, %16, off offset:576 sc1\n\t"
    "global_load_dwordx4 %10, %16, off offset:640 sc1\n\t"
    "global_load_dwordx4 %11, %16, off offset:704 sc1\n\t"
    "global_load_dwordx4 %12, %16, off offset:768 sc1\n\t"
    "global_load_dwordx4 %13, %16, off offset:832 sc1\n\t"
    "global_load_dwordx4 %14, %16, off offset:896 sc1\n\t"
    "global_load_dwordx4 %15, %16, off offset:960 sc1"
    : "=&v"(r[0]), "=&v"(r[1]), "=&v"(r[2]), "=&v"(r[3]),
      "=&v"(r[4]), "=&v"(r[5]), "=&v"(r[6]), "=&v"(r[7]),
      "=&v"(r[8]), "=&v"(r[9]), "=&v"(r[10]), "=&v"(r[11]),
      "=&v"(r[12]), "=&v"(r[13]), "=&v"(r[14]), "=&v"(r[15])
    : "v"(base)
    : "memory");
}
__device__ __forceinline__ void cwait16(floatx4 r[16]){
  asm volatile("s_waitcnt vmcnt(0)"
    : "+v"(r[0]), "+v"(r[1]), "+v"(r[2]), "+v"(r[3]),
      "+v"(r[4]), "+v"(r[5]), "+v"(r[6]), "+v"(r[7]),
      "+v"(r[8]), "+v"(r[9]), "+v"(r[10]), "+v"(r[11]),
      "+v"(r[12]), "+v"(r[13]), "+v"(r[14]), "+v"(r[15])
    :: "memory");
  __builtin_amdgcn_sched_barrier(0);
}

// ---------------- prologue kernels ----------------

__global__ __launch_bounds__(256) void p0_xbf(const float* __restrict__ x,
                                              unsigned short* __restrict__ xbf){
  int idx = (blockIdx.x*256 + threadIdx.x)*4;
  floatx4 f = *(const floatx4*)(x + idx);
  ushort4v u;
  u[0]=f2bf(f[0]); u[1]=f2bf(f[1]); u[2]=f2bf(f[2]); u[3]=f2bf(f[3]);
  *(ushort4v*)(xbf + idx) = u;
}

__global__ __launch_bounds__(256) void p1_wg(const float* __restrict__ Wih,
                                             const float* __restrict__ Whh,
                                             unsigned short* __restrict__ Wg){
  int idx = blockIdx.x*256 + threadIdx.x;
  int n = idx / 768, k = idx - n*768;
  float v = (k < 256) ? Wih[n*256 + k] : Whh[n*512 + (k-256)];
  Wg[idx] = f2bf(v);
}

__global__ __launch_bounds__(256) void p2_T(const float* __restrict__ Win,
                                            const float* __restrict__ Wread,
                                            const float* __restrict__ bread,
                                            const float* __restrict__ bin,
                                            float* __restrict__ T, float* __restrict__ rq){
  if (blockIdx.x < 512){
    int idx = blockIdx.x*256 + threadIdx.x;
    int e = idx >> 9, cc = idx & 511;
    float acc = 0.f;
    for (int dp = 0; dp < 256; ++dp) acc += Win[e*256 + dp] * Wread[dp*512 + cc];
    T[idx] = acc;
  } else {
    int e = threadIdx.x;
    float acc = bin[e];
    for (int dp = 0; dp < 256; ++dp) acc += bread[dp] * Win[e*256 + dp];
    rq[e] = acc;
  }
}

__global__ __launch_bounds__(256) void p3_w2(const float* __restrict__ Win,
                                             const float* __restrict__ Wwrite,
                                             const float* __restrict__ Werase,
                                             const float* __restrict__ Wrg,
                                             const float* __restrict__ Wwg,
                                             const float* __restrict__ bwrite,
                                             const float* __restrict__ berase,
                                             const float* __restrict__ brg,
                                             const float* __restrict__ bwg,
                                             const float* __restrict__ T,
                                             const float* __restrict__ rq,
                                             unsigned short* __restrict__ W2,
                                             float* __restrict__ bias2){
  int bid = blockIdx.x;
  if (bid < 2048){
    int idx = bid*256 + threadIdx.x;
    int j = idx >> 9, cc = idx & 511;
    int h = j >> 8, d = j & 255;
    float acc = 0.f;
    const float* wk = Win + (256 + h*64)*256 + d;
    const float* tp = T + (h*64)*512 + cc;
    for (int i = 0; i < 64; ++i) acc += wk[i*256] * tp[i*512];
    W2[(size_t)j*512 + cc] = f2bf(acc);
  } else if (bid < 2048 + 1568){
    int idx = (bid - 2048)*256 + threadIdx.x;
    int r = idx >> 9, cc = idx & 511;
    float v;
    if      (r < 512) v = Wwrite[r*512 + cc];
    else if (r < 768) v = Werase[(r-512)*512 + cc];
    else if (r == 768) v = Wrg[cc];
    else if (r == 769) v = Wwg[cc];
    else v = 0.f;
    W2[(size_t)(1024 + r)*512 + cc] = f2bf(v);
  } else {
    int j = (bid - 2048 - 1568)*256 + threadIdx.x;
    if (j >= 1808) return;
    float v;
    if (j < 1024){
      int h = j >> 8, d = j & 255;
      float acc = 0.f;
      for (int i = 0; i < 64; ++i) acc += rq[h*64+i] * Win[(256 + h*64 + i)*256 + d];
      v = acc;
    }
    else if (j < 1536) v = bwrite[j - 1024];
    else if (j < 1792) v = berase[j - 1536];
    else if (j == 1792) v = brg[0];
    else if (j == 1793) v = bwg[0];
    else v = 0.f;
    bias2[j] = v;
  }
}

// Fold: column j = d*4 + h (matches mctx u64-packed d-major layout)
__global__ __launch_bounds__(256) void p4_fold(const float* __restrict__ Win,
                                               const float* __restrict__ Wout,
                                               const float* __restrict__ bout,
                                               const float* __restrict__ bin,
                                               unsigned short* __restrict__ Fold,
                                               float* __restrict__ bout2){
  if (blockIdx.x < 1024){
    int idx = blockIdx.x*256 + threadIdx.x;
    int dp = idx >> 10, j = idx & 1023;
    int h = j & 3, d = j >> 2;
    float acc = 0.f;
    const float* wv = Win + (512 + h*64)*256 + d;
    const float* wo = Wout + dp*256 + h*64;
    for (int i = 0; i < 64; ++i) acc += wv[i*256] * wo[i];
    Fold[(size_t)dp*1024 + j] = f2bf(acc);
  } else {
    int dp = threadIdx.x;
    float acc = bout[dp];
    for (int e = 0; e < 256; ++e) acc += Wout[dp*256 + e] * bin[512 + e];
    bout2[dp] = acc;
  }
}

// zero c/h0, biasg = bih + bhh
__global__ __launch_bounds__(256) void p5_init(const float* __restrict__ bih,
                                               const float* __restrict__ bhh,
                                               float* __restrict__ biasg,
                                               float* __restrict__ c,
                                               unsigned short* __restrict__ h0){
  int idx = blockIdx.x*256 + threadIdx.x;
  c[idx] = 0.f; h0[idx] = 0;
  if (idx < 2048) biasg[idx] = bih[idx] + bhh[idx];
}

// ---------------- 16-block group barrier (relaxed L3 atomics, 256B-spaced) ----------------
__device__ __forceinline__ void gbarg(unsigned* cnt, unsigned target){
  __syncthreads();
  if (threadIdx.x == 0){
    __hip_atomic_fetch_add(cnt, 1u, __ATOMIC_RELAXED, AGENT);
    while (__hip_atomic_load(cnt, __ATOMIC_RELAXED, AGENT) < target)
      __builtin_amdgcn_s_sleep(1);
  }
  __builtin_amdgcn_sched_barrier(0);
  __syncthreads();
}

// ---------------- persistent kernel ----------------

// full-load readout (final step only)
__device__ __forceinline__ void do_readout(int mt, int dt, int t,
                                           const unsigned short* __restrict__ mctx,
                                           const unsigned short* __restrict__ Fold,
                                           const float* __restrict__ rgb,
                                           const float* __restrict__ bout2,
                                           const float* __restrict__ x,
                                           float* __restrict__ out, int lane){
  const int lm = lane & 15, lk = (lane >> 4) * 8;
  const unsigned short* ap = mctx + (size_t)(mt*16 + lm)*1024 + lk;
  const unsigned short* bp = Fold + (size_t)(dt*16 + lm)*1024 + lk;
  const int r0 = mt*16 + ((lane >> 4) << 2);
  floatx4 rg = cld4(&rgb[r0]);                     // one 16B coherent load
  V16 a0 = cload16(ap);
  V16 a1 = cload16(ap + 512);
  const bf16x8 av[16] = {BC(a0.v0),BC(a0.v1),BC(a0.v2),BC(a0.v3),BC(a0.v4),BC(a0.v5),BC(a0.v6),BC(a0.v7),
                         BC(a0.v8),BC(a0.v9),BC(a0.v10),BC(a0.v11),BC(a0.v12),BC(a0.v13),BC(a0.v14),BC(a0.v15)};
  const bf16x8 bv[16] = {BC(a1.v0),BC(a1.v1),BC(a1.v2),BC(a1.v3),BC(a1.v4),BC(a1.v5),BC(a1.v6),BC(a1.v7),
                         BC(a1.v8),BC(a1.v9),BC(a1.v10),BC(a1.v11),BC(a1.v12),BC(a1.v13),BC(a1.v14),BC(a1.v15)};
  floatx4 acc = {0,0,0,0};
  #pragma unroll
  for (int kt = 0; kt < 16; ++kt)
    acc = mfma16(av[kt], *(const bf16x8*)(bp + kt*32), acc);
  #pragma unroll
  for (int kt = 0; kt < 16; ++kt)
    acc = mfma16(bv[kt], *(const bf16x8*)(bp + 512 + kt*32), acc);
  const int dp = dt*16 + lm;
  const float bo = bout2[dp];
  #pragma unroll
  for (int q = 0; q < 4; ++q){
    const int bb = r0 + q;
    const size_t oi = ((size_t)bb * S_LEN + (t-1)) * D_DIM + dp;
    out[oi] = x[oi] + rg[q] * (acc[q] + bo);
  }
}

// readout with preloaded Fold first half (in-loop)
__device__ __forceinline__ void do_readout_pre(const bf16x8 f1[16],
                                               int mt, int dt, int t,
                                               const unsigned short* __restrict__ mctx,
                                               const unsigned short* __restrict__ Fold,
                                               const float* __restrict__ rgb,
                                               const float* __restrict__ bout2,
                                               const float* __restrict__ x,
                                               float* __restrict__ out, int lane){
  const int lm = lane & 15, lk = (lane >> 4) * 8;
  const unsigned short* ap = mctx + (size_t)(mt*16 + lm)*1024 + lk;
  const unsigned short* bp = Fold + (size_t)(dt*16 + lm)*1024 + lk;
  const int r0 = mt*16 + ((lane >> 4) << 2);
  floatx4 rg = cld4(&rgb[r0]);                     // one 16B coherent load
  V16 a0 = cload16(ap);
  V16 a1 = cload16(ap + 512);
  const bf16x8 av[16] = {BC(a0.v0),BC(a0.v1),BC(a0.v2),BC(a0.v3),BC(a0.v4),BC(a0.v5),BC(a0.v6),BC(a0.v7),
                         BC(a0.v8),BC(a0.v9),BC(a0.v10),BC(a0.v11),BC(a0.v12),BC(a0.v13),BC(a0.v14),BC(a0.v15)};
  const bf16x8 bv[16] = {BC(a1.v0),BC(a1.v1),BC(a1.v2),BC(a1.v3),BC(a1.v4),BC(a1.v5),BC(a1.v6),BC(a1.v7),
                         BC(a1.v8),BC(a1.v9),BC(a1.v10),BC(a1.v11),BC(a1.v12),BC(a1.v13),BC(a1.v14),BC(a1.v15)};
  floatx4 acc = {0,0,0,0};
  #pragma unroll
  for (int kt = 0; kt < 16; ++kt)
    acc = mfma16(av[kt], f1[kt], acc);
  #pragma unroll
  for (int kt = 0; kt < 16; ++kt)
    acc = mfma16(bv[kt], *(const bf16x8*)(bp + 512 + kt*32), acc);
  const int dp = dt*16 + lm;
  const float bo = bout2[dp];
  #pragma unroll
  for (int q = 0; q < 4; ++q){
    const int bb = r0 + q;
    const size_t oi = ((size_t)bb * S_LEN + (t-1)) * D_DIM + dp;
    out[oi] = x[oi] + rg[q] * (acc[q] + bo);
  }
}

__global__ __launch_bounds__(512, 2) void kmain(
    const float* __restrict__ x,
    const unsigned short* __restrict__ xbf,
    const unsigned short* __restrict__ Wg,
    const float* __restrict__ biasg,
    const unsigned short* __restrict__ W2, const float* __restrict__ bias2,
    const unsigned short* __restrict__ Fold, const float* __restrict__ bout2,
    float* __restrict__ cbuf,
    unsigned short* __restrict__ h0buf, unsigned short* __restrict__ h1buf,
    unsigned short* __restrict__ projB, unsigned short* __restrict__ mctx,
    float* __restrict__ rgbuf, const float* __restrict__ mem0,
    float* __restrict__ memT, float* __restrict__ out,
    unsigned* __restrict__ barcnt)
{
  const int bid = blockIdx.x, tid = threadIdx.x;
  const int lane = tid & 63, wave = tid >> 6;
  const int lm = lane & 15, lk = (lane >> 4) * 8;

  __shared__ float memF[32768];       // 131072 B, XOR-swizzled [n][d]
  __shared__ float scU[5][512];       //  10240 B (AB: ga / D: scores)
  __shared__ float qkW[5][256];       //   5120 B
  __shared__ float er[256];           //   1024 B
  __shared__ float wvs[256];          //   1024 B
  __shared__ float attT[128][8];      //   4096 B
  __shared__ float hL[512];           //   2048 B
  __shared__ float wgS;
  float (*ga)[16][32] = (float (*)[16][32])&scU[0][0];

  const int r = bid >> 4, uc = bid & 15, u0 = uc*32;
  unsigned* gcnt = barcnt + r*64;     // 256B-spaced per-group counter

  for (int i = tid; i < 32768; i += 512){
    const int n = i >> 8, d = i & 255;
    memF[msw(n, d)] = mem0[i];
  }

  unsigned nbar = 0;
  const unsigned short* hr = h0buf;
  unsigned short* hw = h1buf;
  const int g = wave >> 1, colh = wave & 1;
  const int row = r*16 + lm;
  const int slot = uc*8 + wave;       // 0..127 within group

  // ---- weight preload (spills to scratch; measured neutral-positive, R13) ----
  bf16x8 whreg[16];
  {
    const unsigned short* wb = Wg + (size_t)(g*512 + u0 + colh*16 + lm)*768 + lk;
    #pragma unroll
    for (int kt = 0; kt < 16; ++kt) whreg[kt] = *(const bf16x8*)(wb + 256 + kt*32);
  }
  bf16x8 w2reg[16];
  if (slot < 112){
    const unsigned short* bp = W2 + (size_t)(slot*16 + lm)*512 + lk;
    #pragma unroll
    for (int kt = 0; kt < 16; ++kt) w2reg[kt] = *(const bf16x8*)(bp + kt*32);
  } else {
    const unsigned short* bp = Fold + (size_t)((slot-112)*16 + lm)*1024 + lk;
    #pragma unroll
    for (int kt = 0; kt < 16; ++kt) w2reg[kt] = *(const bf16x8*)(bp + kt*32);
  }

  // prologue prefetch: h(-1)=0 buffer + x(0)
  floatx4 hq[16];
  bf16x8 xfr[8];
  cload16_issue(hr + (size_t)row*C_DIM + lk, hq);
  {
    const unsigned short* ax = xbf + ((size_t)row*S_LEN + 0)*D_DIM + lk;
    #pragma unroll
    for (int kt = 0; kt < 8; ++kt) xfr[kt] = *(const bf16x8*)(ax + kt*32);
  }

  for (int t = 0; t < S_LEN; ++t){
    // ---- phase AB: gates GEMM + LSTM ----
    {
      const unsigned short* wbx = Wg + (size_t)(g*512 + u0 + colh*16 + lm)*768 + lk;
      cwait16(hq);
      floatx4 acc = {0,0,0,0};
      #pragma unroll
      for (int kt = 0; kt < 8; ++kt)
        acc = mfma16(xfr[kt], *(const bf16x8*)(wbx + kt*32), acc);
      #pragma unroll
      for (int kt = 0; kt < 16; ++kt)
        acc = mfma16(BC(hq[kt]), whreg[kt], acc);
      const int rr0 = (lane >> 4) << 2;
      #pragma unroll
      for (int q = 0; q < 4; ++q) ga[g][rr0+q][colh*16 + lm] = acc[q];
      __syncthreads();
      if (tid < 256){
        const int ri = tid >> 4, cp = (tid & 15) * 2;
        const int b = r*16 + ri, u = u0 + cp;
        floatx2 bg0 = *(const floatx2*)&biasg[u];
        floatx2 bg1 = *(const floatx2*)&biasg[512 + u];
        floatx2 bg2 = *(const floatx2*)&biasg[1024 + u];
        floatx2 bg3 = *(const floatx2*)&biasg[1536 + u];
        const float gi0 = ga[0][ri][cp]   + bg0[0];
        const float gf0 = ga[1][ri][cp]   + bg1[0];
        const float gg0 = ga[2][ri][cp]   + bg2[0];
        const float go0 = ga[3][ri][cp]   + bg3[0];
        const float gi1 = ga[0][ri][cp+1] + bg0[1];
        const float gf1 = ga[1][ri][cp+1] + bg1[1];
        const float gg1 = ga[2][ri][cp+1] + bg2[1];
        const float go1 = ga[3][ri][cp+1] + bg3[1];
        const int ci2 = b*512 + u;
        floatx2 cv = *(const floatx2*)&cbuf[ci2];
        const float cn0 = sigm(gf0) * cv[0] + sigm(gi0) * tanhf(gg0);
        const float cn1 = sigm(gf1) * cv[1] + sigm(gi1) * tanhf(gg1);
        floatx2 cw; cw[0] = cn0; cw[1] = cn1;
        *(floatx2*)&cbuf[ci2] = cw;
        const unsigned hv2 = (unsigned)f2bf(sigm(go0) * tanhf(cn0))
                           | ((unsigned)f2bf(sigm(go1) * tanhf(cn1)) << 16);
        ast32((unsigned*)hw + (ci2 >> 1), hv2);
      }
    }
    gbarg(gcnt, (++nbar)*16u);
    // ---- phase C: 112 proj tiles + 16 readouts ----
    {
      if (slot < 112){
        const unsigned short* ap = hw + (size_t)(r*16 + lm)*512 + lk;
        V16 av16 = cload16(ap);
        const bf16x8 av[16] = {BC(av16.v0),BC(av16.v1),BC(av16.v2),BC(av16.v3),BC(av16.v4),BC(av16.v5),BC(av16.v6),BC(av16.v7),
                               BC(av16.v8),BC(av16.v9),BC(av16.v10),BC(av16.v11),BC(av16.v12),BC(av16.v13),BC(av16.v14),BC(av16.v15)};
        floatx4 acc = {0,0,0,0};
        #pragma unroll
        for (int kt = 0; kt < 16; ++kt)
          acc = mfma16(av[kt], w2reg[kt], acc);
        const int r0 = r*16 + ((lane >> 4) << 2);
        const int cc = slot*16 + lm;
        const float bv = bias2[cc];
        const bool sg = (cc >= 1536);
        #pragma unroll
        for (int q = 0; q < 4; ++q){
          float v = acc[q] + bv;
          if (sg) v = sigm(v);
          sst16(&projB[(size_t)(r0 + q)*PROJS + cc], f2bf(v));
        }
      } else if (t >= 1){
        do_readout_pre(w2reg, r, slot - 112, t, mctx, Fold, rgbuf, bout2, x, out, lane);
      }
    }
    gbarg(gcnt, (++nbar)*16u);
    // ---- phase D: attention + memory update (block = batch bid) ----
    {
      const unsigned long long* p64 = (const unsigned long long*)(projB + (size_t)bid*PROJS);
      if (tid < 448){
        unsigned long long u2 = ald64(p64 + tid);
        float e0 = bf2f((unsigned short)(u2 & 0xFFFFu));
        float e1 = bf2f((unsigned short)((u2 >> 16) & 0xFFFFu));
        float e2 = bf2f((unsigned short)((u2 >> 32) & 0xFFFFu));
        float e3 = bf2f((unsigned short)(u2 >> 48));
        const int j = tid*4;
        if (j < 1024){ float* q = &qkW[j>>8][j&255]; q[0]=e0; q[1]=e1; q[2]=e2; q[3]=e3; }
        else if (j < 1280){ float* q = &qkW[4][j-1024]; q[0]=e0; q[1]=e1; q[2]=e2; q[3]=e3; }
        else if (j < 1536){ float* q = &wvs[j-1280]; q[0]=e0; q[1]=e1; q[2]=e2; q[3]=e3; }
        else { float* q = &er[j-1536]; q[0]=e0; q[1]=e1; q[2]=e2; q[3]=e3; }
      } else {
        const int i = tid - 448;
        const unsigned long long* h64 = (const unsigned long long*)(hw + (size_t)bid*C_DIM);
        unsigned long long a = ald64(h64 + 2*i), b = ald64(h64 + 2*i + 1);
        float* q = &hL[i*8];
        q[0]=bf2f((unsigned short)(a & 0xFFFFu)); q[1]=bf2f((unsigned short)((a>>16)&0xFFFFu));
        q[2]=bf2f((unsigned short)((a>>32)&0xFFFFu)); q[3]=bf2f((unsigned short)(a>>48));
        q[4]=bf2f((unsigned short)(b & 0xFFFFu)); q[5]=bf2f((unsigned short)((b>>16)&0xFFFFu));
        q[6]=bf2f((unsigned short)((b>>32)&0xFFFFu)); q[7]=bf2f((unsigned short)(b>>48));
      }
      __syncthreads();
      if (wave >= 6){
        const int rowW = 1792 + (wave - 6);
        const unsigned short* wrow = W2 + (size_t)rowW*512 + lane*8;
        const float* hp = &hL[lane*8];
        float s = 0.f;
        #pragma unroll
        for (int c = 0; c < 8; ++c) s += hp[c] * bf2f(wrow[c]);
        #pragma unroll
        for (int off = 32; off; off >>= 1) s += __shfl_xor(s, off);
        if (lane == 0){
          const float v = sigm(s + bias2[rowW]);
          if (wave == 6) ast32(&rgbuf[bid], __float_as_uint(v));
          else wgS = v;
        }
      }
      // pass1: scores (vectorized b128, swizzle-aware)
      {
        const int n = tid & 127, quarter = tid >> 7, db = quarter*64;
        const int c7 = n & 7;
        const float* mrow = &memF[n << 8];
        floatx4 A0={0,0,0,0},A1={0,0,0,0},A2={0,0,0,0},A3={0,0,0,0},A4={0,0,0,0};
        #pragma unroll 4
        for (int i = 0; i < 64; i += 4){
          floatx4 m4 = *(const floatx4*)(mrow + ((((db+i)>>2) ^ c7) << 2));
          floatx4 q0 = *(const floatx4*)&qkW[0][db+i];
          floatx4 q1 = *(const floatx4*)&qkW[1][db+i];
          floatx4 q2 = *(const floatx4*)&qkW[2][db+i];
          floatx4 q3 = *(const floatx4*)&qkW[3][db+i];
          floatx4 qw = *(const floatx4*)&qkW[4][db+i];
          A0 += m4*q0; A1 += m4*q1; A2 += m4*q2; A3 += m4*q3; A4 += m4*qw;
        }
        scU[0][tid] = A0[0]+A0[1]+A0[2]+A0[3];
        scU[1][tid] = A1[0]+A1[1]+A1[2]+A1[3];
        scU[2][tid] = A2[0]+A2[1]+A2[2]+A2[3];
        scU[3][tid] = A3[0]+A3[1]+A3[2]+A3[3];
        scU[4][tid] = A4[0]+A4[1]+A4[2]+A4[3];
      }
      __syncthreads();
      if (tid < 128){
        #pragma unroll
        for (int j = 0; j < 5; ++j){
          float v = scU[j][tid] + scU[j][tid+128] + scU[j][tid+256] + scU[j][tid+384];
          scU[j][tid] = (j < 4) ? v * 0.125f : v;
        }
      }
      __syncthreads();
      {
        const int w = tid >> 6, l = tid & 63;
        if (w < 5){
          const int j = w;
          float v0 = scU[j][l], v1 = scU[j][l + 64];
          float mx = fmaxf(v0, v1);
          #pragma unroll
          for (int off = 32; off; off >>= 1) mx = fmaxf(mx, __shfl_xor(mx, off));
          float e0 = __expf(v0 - mx), e1 = __expf(v1 - mx);
          float sm = e0 + e1;
          #pragma unroll
          for (int off = 32; off; off >>= 1) sm += __shfl_xor(sm, off);
          float inv = 1.f / sm;
          attT[l][j] = e0 * inv; attT[l + 64][j] = e1 * inv;
        }
      }
      __syncthreads();
      // prefetch x(t+1) + issue h(t) coherent loads — latency hides under pass2
      {
        const int tn = (t+1 < S_LEN) ? t+1 : t;
        const unsigned short* ax = xbf + ((size_t)row*S_LEN + tn)*D_DIM + lk;
        #pragma unroll
        for (int kt = 0; kt < 8; ++kt) xfr[kt] = *(const bf16x8*)(ax + kt*32);
        cload16_issue(hw + (size_t)row*C_DIM + lk, hq);
      }
      // fused pass2 + memory update
      {
        const float wgv = wgS;
        const int dlow = lane & 7, ng = lane >> 3;
        const int dblk = wave*8 + dlow;
        const int pblk = dblk ^ ng;
        const int d4 = dblk*4;
        floatx4 er4 = *(const floatx4*)&er[d4];
        floatx4 wv4 = *(const floatx4*)&wvs[d4];
        floatx4 A0={0,0,0,0},A1={0,0,0,0},A2={0,0,0,0},A3={0,0,0,0};
        #pragma unroll 4
        for (int k = 0; k < 16; ++k){
          const int n = ng + k*8;
          float* maddr = &memF[(n << 8) + (pblk << 2)];
          floatx4 m = *(const floatx4*)maddr;
          floatx4 a4 = *(const floatx4*)&attT[n][0];
          const float aw = attT[n][4];
          A0 += a4[0]*m; A1 += a4[1]*m; A2 += a4[2]*m; A3 += a4[3]*m;
          m = m * (1.f - aw*er4) + (wgv*aw) * wv4;
          *(floatx4*)maddr = m;
        }
        #pragma unroll
        for (int off = 8; off <= 32; off <<= 1){
          #pragma unroll
          for (int c = 0; c < 4; ++c){
            A0[c] += __shfl_xor(A0[c], off);
            A1[c] += __shfl_xor(A1[c], off);
            A2[c] += __shfl_xor(A2[c], off);
            A3[c] += __shfl_xor(A3[c], off);
          }
        }
        if (ng == 0){
          unsigned long long* mrow2 = (unsigned long long*)(mctx + (size_t)bid*1024);
          #pragma unroll
          for (int dd = 0; dd < 4; ++dd){
            const unsigned lo = (unsigned)f2bf(A0[dd]) | ((unsigned)f2bf(A1[dd]) << 16);
            const unsigned hi = (unsigned)f2bf(A2[dd]) | ((unsigned)f2bf(A3[dd]) << 16);
            ast64(mrow2 + d4 + dd, (unsigned long long)lo | ((unsigned long long)hi << 32));
          }
        }
      }
    }
    unsigned short* tmp = (unsigned short*)hr; hr = hw; hw = tmp;
  }
  gbarg(gcnt, (++nbar)*16u);
  // final readout (t = S_LEN): one tile per block (mt=r, dt=uc)
  if (wave == 0)
    do_readout(r, uc, S_LEN, mctx, Fold, rgbuf, bout2, x, out, lane);
  for (int i = tid; i < 32768; i += 512){
    const int n = i >> 8, d = i & 255;
    memT[(size_t)bid * 32768 + i] = memF[msw(n, d)];
  }
}

// ---------------- host ----------------

extern "C" void kernel_launch(void* const* d_in, const int* in_sizes, int n_in,
                              void* d_out, int out_size, void* d_ws, size_t ws_size,
                              hipStream_t stream){
  const float* x      = (const float*)d_in[0];
  const float* mem0   = (const float*)d_in[1];
  const float* Wih    = (const float*)d_in[2];
  const float* Whh    = (const float*)d_in[3];
  const float* bih    = (const float*)d_in[4];
  const float* bhh    = (const float*)d_in[5];
  const float* Wread  = (const float*)d_in[6];
  const float* bread  = (const float*)d_in[7];
  const float* Wwrite = (const float*)d_in[8];
  const float* bwrite = (const float*)d_in[9];
  const float* Werase = (const float*)d_in[10];
  const float* berase = (const float*)d_in[11];
  const float* Win    = (const float*)d_in[12];
  const float* bin    = (const float*)d_in[13];
  const float* Wout   = (const float*)d_in[14];
  const float* bout   = (const float*)d_in[15];
  const float* Wrg    = (const float*)d_in[16];
  const float* brg    = (const float*)d_in[17];
  const float* Wwg    = (const float*)d_in[18];
  const float* bwg    = (const float*)d_in[19];
  float* out = (float*)d_out;
  float* memT = out + (size_t)B_SZ * S_LEN * D_DIM;

  char* ws = (char*)d_ws;
  size_t off = 0;
  auto alloc = [&](size_t bytes) -> void* {
    void* p = ws + off; off += (bytes + 511) & ~(size_t)511; return p;
  };
  unsigned short* xbf  = (unsigned short*)alloc((size_t)B_SZ*S_LEN*D_DIM*2);
  unsigned short* Wg   = (unsigned short*)alloc((size_t)2048*768*2);
  unsigned short* W2   = (unsigned short*)alloc((size_t)1808*512*2);
  unsigned short* Fold = (unsigned short*)alloc((size_t)256*1024*2);
  float* T     = (float*)alloc((size_t)256*512*4);
  float* rq    = (float*)alloc(256*4);
  float* bias2 = (float*)alloc(1808*4);
  float* bout2 = (float*)alloc(256*4);
  float* biasg = (float*)alloc(2048*4);
  float* cbuf  = (float*)alloc((size_t)256*512*4);
  unsigned short* h0 = (unsigned short*)alloc((size_t)256*512*2);
  unsigned short* h1 = (unsigned short*)alloc((size_t)256*512*2);
  unsigned short* projB = (unsigned short*)alloc((size_t)256*PROJS*2);
  unsigned short* mctx = (unsigned short*)alloc((size_t)256*1024*2);
  float* rgbuf = (float*)alloc(256*4);
  unsigned* barcnt = (unsigned*)alloc(16384);
  (void)ws_size; (void)in_sizes; (void)n_in; (void)out_size;

  (void)hipMemsetAsync(barcnt, 0, 16384, stream);
  p0_xbf <<<16384, 256, 0, stream>>>(x, xbf);
  p1_wg  <<<6144, 256, 0, stream>>>(Wih, Whh, Wg);
  p2_T   <<<513,  256, 0, stream>>>(Win, Wread, bread, bin, T, rq);
  p3_w2  <<<3624, 256, 0, stream>>>(Win, Wwrite, Werase, Wrg, Wwg, bwrite, berase, brg, bwg, T, rq, W2, bias2);
  p4_fold<<<1025, 256, 0, stream>>>(Win, Wout, bout, bin, Fold, bout2);
  p5_init<<<512,  256, 0, stream>>>(bih, bhh, biasg, cbuf, h0);

  kmain<<<NBLK, 512, 0, stream>>>(x, xbf, Wg, biasg, W2, bias2, Fold, bout2,
                                  cbuf, h0, h1, projB, mctx, rgbuf, mem0, memT, out, barcnt);
}